// Round 8
// baseline (145.767 us; speedup 1.0000x reference)
//
#include <hip/hip_runtime.h>

// out[b,o] = radius * (1/sqrt(K)) * sum_k cos(c*(w[o,k]-x[b,k])),  c = 2*pi/8
//          = radius * (1/sqrt(K)) * sum_k [cos(cx)cos(cw) + sin(cx)sin(cw)]
// B=2048, K=32768, O=10.
// Round 8: LDS-staged x. Round 7's fragment-order global loads were 16x64B
// scattered segments per instruction (~131K interleaved 64B streams grid-wide,
// poor DRAM burst density). Now: linear dense global loads (512B/row-chunk) ->
// reg -> XOR-swizzled ds_write -> fragment-order ds_read_b128 (conflict-free).
// Async-stage split: step s+1 loads fly under step s compute. MFMA unchanged.

typedef _Float16 half2_t __attribute__((ext_vector_type(2)));
typedef _Float16 half8_t __attribute__((ext_vector_type(8)));
typedef float f32x4 __attribute__((ext_vector_type(4)));

#define K_DIM 32768
#define B_DIM 2048
#define O_DIM 10
#define NWIN 2048               // one window = 16 k x 16 rows
#define KCH 64                  // K-chunks
#define WPC (NWIN / KCH)        // 32 windows per chunk
#define BK 128                  // k per staging step = 8 windows
#define STEPS (WPC / 8)         // 4
#define MTILES (B_DIM / 64)     // 32
#define THREADS 256
#define INV_SQRT_K 0.005524271728019903f

// hardware v_sin/v_cos take REVOLUTIONS: sin(2*pi*r). c*x radians -> r = x/8.

__device__ __forceinline__ half2_t pack_cs(float c, float s) {
    return __builtin_bit_cast(half2_t, __builtin_amdgcn_cvt_pkrtz(c, s));
}

// A fragment from 4 consecutive x floats: (cos,sin) f16 pairs -> 8 f16
__device__ __forceinline__ half8_t afrag(float4 xc) {
    const float* xf = (const float*)&xc;
    uint4 au;
    unsigned u[4];
    #pragma unroll
    for (int j = 0; j < 4; ++j) {
        float rr = xf[j] * 0.125f;            // revolutions
        u[j] = __builtin_bit_cast(unsigned,
                   pack_cs(__builtin_amdgcn_cosf(rr),
                           __builtin_amdgcn_sinf(rr)));
    }
    au.x = u[0]; au.y = u[1]; au.z = u[2]; au.w = u[3];
    return __builtin_bit_cast(half8_t, au);
}

// B-fragment table: for window t, lane l: 16 bytes = (cos,sin) f16 pairs of
// w[o = l&15][k = t*16 + (l>>4)*4 + 0..3]; o >= 10 -> zeros.
__global__ void wtab_kernel(const float* __restrict__ w,
                            uint4* __restrict__ wtab) {
    int gid = blockIdx.x * THREADS + threadIdx.x;    // 2048*64 = 131072 exact
    int t = gid >> 6, l = gid & 63;
    int o = l & 15, kg = l >> 4;
    int k = t * 16 + kg * 4;
    uint4 v; v.x = v.y = v.z = v.w = 0u;
    if (o < O_DIM) {
        const float4 wv = *(const float4*)(w + (size_t)o * K_DIM + k);
        const float* wp = (const float*)&wv;
        unsigned u[4];
        #pragma unroll
        for (int j = 0; j < 4; ++j) {
            float rr = wp[j] * 0.125f;
            u[j] = __builtin_bit_cast(unsigned,
                       pack_cs(__builtin_amdgcn_cosf(rr),
                               __builtin_amdgcn_sinf(rr)));
        }
        v.x = u[0]; v.y = u[1]; v.z = u[2]; v.w = u[3];
    }
    wtab[gid] = v;
}

__global__ __launch_bounds__(THREADS) void gsim_mfma(
        const float* __restrict__ x,
        const uint4* __restrict__ wtab,
        float* __restrict__ part) {
    __shared__ float xtile[64 * BK];     // 32 KB, XOR-swizzled columns

    const int bid = blockIdx.x;
    const int mt = bid & (MTILES - 1);   // m-tile (fast)
    const int kc = bid >> 5;             // k-chunk
    const int t = threadIdx.x;
    const int wave = t >> 6, lane = t & 63;
    const int o = lane & 15, kg = lane >> 4;

    // ---- staging geometry (constant per thread) ----
    // 16B slot s = i*256 + t (i = issue 0..7): row = i*8 + (t>>5), c16 = t&31.
    const int srow = t >> 5;             // 0..7
    const int sc16 = t & 31;             // 0..31
    // ds_write byte addr for issue i: i*4096 + srow*512 + ((sc16^srow)<<4)
    // (row&7 == srow because i*8 is 0 mod 8)
    const int ldsw0 = srow * 512 + ((sc16 ^ srow) << 4);
    // global float addr: (mt*64 + i*8 + srow)*K_DIM + kc*512 + s*128 + sc16*4
    const float* gbase = x + ((size_t)(mt * 64 + srow) * K_DIM) + kc * 512 + sc16 * 4;

    // ---- compute geometry ----
    const int rowf = wave * 16 + o;      // fragment row in tile (row&7 == o&7)
    const int lds_rbase = rowf * 512;
    const int o7 = o & 7;

    const uint4* bp = wtab + (size_t)(kc * WPC) * 64 + lane;

    f32x4 acc = {0.f, 0.f, 0.f, 0.f};
    float4 gbuf[2][8];

    // prologue: step 0 loads (dense: consecutive lanes cover 512B per row-chunk)
    #pragma unroll
    for (int i = 0; i < 8; ++i)
        gbuf[0][i] = *(const float4*)(gbase + (size_t)i * 8 * K_DIM);

    #pragma unroll
    for (int s = 0; s < STEPS; ++s) {
        __syncthreads();                 // LDS free (previous compute done)
        // write step s tile (compiler inserts vmcnt waits; loads issued a full
        // step earlier so no stall)
        #pragma unroll
        for (int i = 0; i < 8; ++i)
            *(float4*)((char*)xtile + i * 4096 + ldsw0) = gbuf[s & 1][i];
        // issue step s+1 loads now; they fly under the compute below
        if (s + 1 < STEPS) {
            #pragma unroll
            for (int i = 0; i < 8; ++i)
                gbuf[(s + 1) & 1][i] =
                    *(const float4*)(gbase + (s + 1) * BK + (size_t)i * 8 * K_DIM);
        }
        __syncthreads();                 // tile visible

        #pragma unroll
        for (int tw = 0; tw < 8; ++tw) {
            uint4 bc = bp[(size_t)(s * 8 + tw) * 64];
            float4 xv = *(const float4*)((const char*)xtile + lds_rbase
                            + ((((tw << 2) + kg) ^ o7) << 4));
            half8_t a = afrag(xv);
            acc = __builtin_amdgcn_mfma_f32_16x16x32_f16(
                      a, __builtin_bit_cast(half8_t, bc), acc, 0, 0, 0);
        }
    }

    // C/D layout: col = lane&15, row_in_tile = (lane>>4)*4 + reg  [m89]
    const int rbase = mt * 64 + wave * 16 + kg * 4;
    float* pp = part + ((size_t)kc * B_DIM + rbase) * 16 + o;
    #pragma unroll
    for (int reg = 0; reg < 4; ++reg)
        pp[(size_t)reg * 16] = acc[reg];
}

__global__ void finalize_kernel(const float* __restrict__ part,
                                const float* __restrict__ radius,
                                float* __restrict__ out) {
    int gid = blockIdx.x * THREADS + threadIdx.x;    // 2048*16 = 32768 exact
    int b = gid >> 4, o = gid & 15;
    if (o >= O_DIM) return;
    float s = 0.f;
    #pragma unroll 8
    for (int kc = 0; kc < KCH; ++kc)
        s += part[(size_t)kc * (B_DIM * 16) + gid];
    out[(size_t)b * O_DIM + o] = s * radius[0] * INV_SQRT_K;
}

extern "C" void kernel_launch(void* const* d_in, const int* in_sizes, int n_in,
                              void* d_out, int out_size, void* d_ws, size_t ws_size,
                              hipStream_t stream) {
    const float* x      = (const float*)d_in[0];
    const float* w      = (const float*)d_in[1];
    const float* radius = (const float*)d_in[2];
    float* out = (float*)d_out;

    // ws: wtab[2048][64] uint4 (2 MB) | part[64][2048][16] f32 (8 MB)
    uint4* wtab = (uint4*)d_ws;
    float* part = (float*)((char*)d_ws + (size_t)NWIN * 64 * 16);

    hipLaunchKernelGGL(wtab_kernel, dim3(NWIN * 64 / THREADS), dim3(THREADS),
                       0, stream, w, wtab);
    hipLaunchKernelGGL(gsim_mfma, dim3(MTILES * KCH), dim3(THREADS),
                       0, stream, x, wtab, part);
    hipLaunchKernelGGL(finalize_kernel, dim3(B_DIM * 16 / THREADS), dim3(THREADS),
                       0, stream, part, radius, out);
}

// Round 9
// 62.690 us; speedup vs baseline: 2.3252x; 2.3252x over previous
//
#include <hip/hip_runtime.h>

// out[b,o] = radius * (1/sqrt(K)) * sum_k cos(c*(w[o,k]-x[b,k])),  c = 2*pi/8
//          = radius * (1/sqrt(K)) * sum_k [cos(cx)cos(cw) + sin(cx)sin(cw)]
// B=2048, K=32768, O=10.
// Round 9: round-7 register pipeline (unroll 1 -- round 8 showed full unroll
// lets the compiler sink prefetches and serialize loads), with 4-window groups:
// each lane loads 64 B contiguous x (4 consecutive float4), MFMA m of the group
// uses float4 #m. wtab rebuilt with the same k-permutation (A/B mirrored).
// Per-row in-flight burst: 128 B -> 512 B for DRAM page locality.

typedef _Float16 half2_t __attribute__((ext_vector_type(2)));
typedef _Float16 half8_t __attribute__((ext_vector_type(8)));
typedef float f32x4 __attribute__((ext_vector_type(4)));

#define K_DIM 32768
#define B_DIM 2048
#define O_DIM 10
#define NWIN 2048               // windows; one window = 16 x-ks (one MFMA)
#define KCH 64                  // K-chunks
#define WPC (NWIN / KCH)        // 32 windows per chunk
#define GROUPS (WPC / 4)        // 8 groups of 4 windows per chunk
#define MTILES (B_DIM / 64)     // 32
#define THREADS 256
#define INV_SQRT_K 0.005524271728019903f

// hardware v_sin/v_cos take REVOLUTIONS: sin(2*pi*r). c*x radians -> r = x/8.

__device__ __forceinline__ half2_t pack_cs(float c, float s) {
    return __builtin_bit_cast(half2_t, __builtin_amdgcn_cvt_pkrtz(c, s));
}

// A fragment from 4 consecutive x floats: (cos,sin) f16 pairs -> 8 f16
__device__ __forceinline__ half8_t afrag(float4 xc) {
    const float* xf = (const float*)&xc;
    uint4 au;
    unsigned u[4];
    #pragma unroll
    for (int j = 0; j < 4; ++j) {
        float rr = xf[j] * 0.125f;            // revolutions
        u[j] = __builtin_bit_cast(unsigned,
                   pack_cs(__builtin_amdgcn_cosf(rr),
                           __builtin_amdgcn_sinf(rr)));
    }
    au.x = u[0]; au.y = u[1]; au.z = u[2]; au.w = u[3];
    return __builtin_bit_cast(half8_t, au);
}

// B-fragment table with the GROUPED k-mapping: window t = (g=t>>2, m=t&3);
// lane l (o=l&15, kg=l>>4) holds (cos,sin) of w[o][k], k = g*64+kg*16+m*4 ..+3.
// Matches the A-side: lane's 64B x run [g*64+kg*16 .. +15], float4 #m.
__global__ void wtab_kernel(const float* __restrict__ w,
                            uint4* __restrict__ wtab) {
    int gid = blockIdx.x * THREADS + threadIdx.x;    // 2048*64 = 131072 exact
    int t = gid >> 6, l = gid & 63;
    int o = l & 15, kg = l >> 4;
    int k = (t >> 2) * 64 + kg * 16 + (t & 3) * 4;
    uint4 v; v.x = v.y = v.z = v.w = 0u;
    if (o < O_DIM) {
        const float4 wv = *(const float4*)(w + (size_t)o * K_DIM + k);
        const float* wp = (const float*)&wv;
        unsigned u[4];
        #pragma unroll
        for (int j = 0; j < 4; ++j) {
            float rr = wp[j] * 0.125f;
            u[j] = __builtin_bit_cast(unsigned,
                       pack_cs(__builtin_amdgcn_cosf(rr),
                               __builtin_amdgcn_sinf(rr)));
        }
        v.x = u[0]; v.y = u[1]; v.z = u[2]; v.w = u[3];
    }
    wtab[gid] = v;
}

__global__ __launch_bounds__(THREADS) void gsim_mfma(
        const float* __restrict__ x,
        const uint4* __restrict__ wtab,
        float* __restrict__ part) {
    const int bid = blockIdx.x;
    const int mt = bid & (MTILES - 1);   // m-tile (fast)
    const int kc = bid >> 5;             // k-chunk
    const int t = threadIdx.x;
    const int wave = t >> 6, lane = t & 63;
    const int o = lane & 15, kg = lane >> 4;

    // lane's x base: row (mt*64 + wave*16 + o), 64B run per group
    const int row = mt * 64 + wave * 16 + o;
    const float4* xp = (const float4*)(x + (size_t)row * K_DIM + kc * 512 + kg * 16);
    // group g float4 #m: xp[g*16 + m]   (64 floats per group / 4)
    const uint4* bp = wtab + (size_t)(kc * WPC) * 64 + lane;
    // group g window m: bp[(g*4+m)*64]

    f32x4 acc = {0.f, 0.f, 0.f, 0.f};

    // prologue: group 0 (4 contiguous float4 per lane = 64B burst)
    float4 xc0 = xp[0], xc1 = xp[1], xc2 = xp[2], xc3 = xp[3];
    uint4  bc0 = bp[0], bc1 = bp[64], bc2 = bp[128], bc3 = bp[192];

    #pragma unroll 1
    for (int g = 0; g < GROUPS; ++g) {
        const int ng = (g + 1 < GROUPS) ? (g + 1) : g;  // last: harmless reload
        // prefetch next group's 64B x run + 4 wtab fragments
        float4 xn0 = xp[ng * 16],     xn1 = xp[ng * 16 + 1],
               xn2 = xp[ng * 16 + 2], xn3 = xp[ng * 16 + 3];
        uint4  bn0 = bp[(size_t)ng * 256],       bn1 = bp[(size_t)ng * 256 + 64],
               bn2 = bp[(size_t)ng * 256 + 128], bn3 = bp[(size_t)ng * 256 + 192];

        acc = __builtin_amdgcn_mfma_f32_16x16x32_f16(
                  afrag(xc0), __builtin_bit_cast(half8_t, bc0), acc, 0, 0, 0);
        acc = __builtin_amdgcn_mfma_f32_16x16x32_f16(
                  afrag(xc1), __builtin_bit_cast(half8_t, bc1), acc, 0, 0, 0);
        acc = __builtin_amdgcn_mfma_f32_16x16x32_f16(
                  afrag(xc2), __builtin_bit_cast(half8_t, bc2), acc, 0, 0, 0);
        acc = __builtin_amdgcn_mfma_f32_16x16x32_f16(
                  afrag(xc3), __builtin_bit_cast(half8_t, bc3), acc, 0, 0, 0);

        xc0 = xn0; xc1 = xn1; xc2 = xn2; xc3 = xn3;
        bc0 = bn0; bc1 = bn1; bc2 = bn2; bc3 = bn3;
    }

    // C/D layout: col = lane&15, row_in_tile = (lane>>4)*4 + reg  [m89]
    const int rbase = mt * 64 + wave * 16 + kg * 4;
    float* pp = part + ((size_t)kc * B_DIM + rbase) * 16 + o;
    #pragma unroll
    for (int reg = 0; reg < 4; ++reg)
        pp[(size_t)reg * 16] = acc[reg];
}

__global__ void finalize_kernel(const float* __restrict__ part,
                                const float* __restrict__ radius,
                                float* __restrict__ out) {
    int gid = blockIdx.x * THREADS + threadIdx.x;    // 2048*16 = 32768 exact
    int b = gid >> 4, o = gid & 15;
    if (o >= O_DIM) return;
    float s = 0.f;
    #pragma unroll 8
    for (int kc = 0; kc < KCH; ++kc)
        s += part[(size_t)kc * (B_DIM * 16) + gid];
    out[(size_t)b * O_DIM + o] = s * radius[0] * INV_SQRT_K;
}

extern "C" void kernel_launch(void* const* d_in, const int* in_sizes, int n_in,
                              void* d_out, int out_size, void* d_ws, size_t ws_size,
                              hipStream_t stream) {
    const float* x      = (const float*)d_in[0];
    const float* w      = (const float*)d_in[1];
    const float* radius = (const float*)d_in[2];
    float* out = (float*)d_out;

    // ws: wtab[2048][64] uint4 (2 MB) | part[64][2048][16] f32 (8 MB)
    uint4* wtab = (uint4*)d_ws;
    float* part = (float*)((char*)d_ws + (size_t)NWIN * 64 * 16);

    hipLaunchKernelGGL(wtab_kernel, dim3(NWIN * 64 / THREADS), dim3(THREADS),
                       0, stream, w, wtab);
    hipLaunchKernelGGL(gsim_mfma, dim3(MTILES * KCH), dim3(THREADS),
                       0, stream, x, wtab, part);
    hipLaunchKernelGGL(finalize_kernel, dim3(B_DIM * 16 / THREADS), dim3(THREADS),
                       0, stream, part, radius, out);
}

// Round 10
// 55.882 us; speedup vs baseline: 2.6085x; 1.1218x over previous
//
#include <hip/hip_runtime.h>

// out[b,o] = radius * (1/sqrt(K)) * sum_k cos(c*(w[o,k]-x[b,k])),  c = 2*pi/8
//          = radius * (1/sqrt(K)) * sum_k [cos(cx)cos(cw) + sin(cx)sin(cw)]
// B=2048, K=32768, O=10.
// Round 10: round-7 main loop verbatim (validated 60.3us / absmax 0.5), but
// the part[]/finalize round-trip (16 MB + 1 dispatch) is replaced by a direct
// f32 atomicAdd epilogue, and d_out zero-init is folded into wtab_kernel.
// 2 dispatches total.

typedef _Float16 half2_t __attribute__((ext_vector_type(2)));
typedef _Float16 half8_t __attribute__((ext_vector_type(8)));
typedef float f32x4 __attribute__((ext_vector_type(4)));

#define K_DIM 32768
#define B_DIM 2048
#define O_DIM 10
#define NWIN 2048               // windows; one window = 16 x-ks = 32 K'-elems
#define KCH 64                  // K-chunks
#define WPC (NWIN / KCH)        // 32 windows per chunk
#define ITERS (WPC / 2)         // 16 iterations x 2 windows
#define MTILES (B_DIM / 64)     // 32 blocks of 64 rows
#define THREADS 256
#define INV_SQRT_K 0.005524271728019903f

// hardware v_sin/v_cos take REVOLUTIONS: sin(2*pi*r). c*x radians -> r = x/8.

__device__ __forceinline__ half2_t pack_cs(float c, float s) {
    return __builtin_bit_cast(half2_t, __builtin_amdgcn_cvt_pkrtz(c, s));
}

// A fragment from 4 consecutive x floats: (cos,sin) f16 pairs -> 8 f16
__device__ __forceinline__ half8_t afrag(float4 xc) {
    const float* xf = (const float*)&xc;
    uint4 au;
    unsigned u[4];
    #pragma unroll
    for (int j = 0; j < 4; ++j) {
        float rr = xf[j] * 0.125f;            // revolutions
        u[j] = __builtin_bit_cast(unsigned,
                   pack_cs(__builtin_amdgcn_cosf(rr),
                           __builtin_amdgcn_sinf(rr)));
    }
    au.x = u[0]; au.y = u[1]; au.z = u[2]; au.w = u[3];
    return __builtin_bit_cast(half8_t, au);
}

// B-fragment table: for window t, lane l: 16 bytes = (cos,sin) f16 pairs of
// w[o = l&15][k = t*16 + (l>>4)*4 + 0..3]; o >= 10 -> zeros.
// Blocks 0..79 additionally zero d_out (20480 = 80*256 floats) -- harness
// poisons d_out once and never re-poisons between graph replays.
__global__ void wtab_kernel(const float* __restrict__ w,
                            uint4* __restrict__ wtab,
                            float* __restrict__ out) {
    if (blockIdx.x < (B_DIM * O_DIM) / THREADS)
        out[blockIdx.x * THREADS + threadIdx.x] = 0.f;

    int gid = blockIdx.x * THREADS + threadIdx.x;    // 2048*64 = 131072 exact
    int t = gid >> 6, l = gid & 63;
    int o = l & 15, kg = l >> 4;
    int k = t * 16 + kg * 4;
    uint4 v; v.x = v.y = v.z = v.w = 0u;
    if (o < O_DIM) {
        const float4 wv = *(const float4*)(w + (size_t)o * K_DIM + k);
        const float* wp = (const float*)&wv;
        unsigned u[4];
        #pragma unroll
        for (int j = 0; j < 4; ++j) {
            float rr = wp[j] * 0.125f;
            u[j] = __builtin_bit_cast(unsigned,
                       pack_cs(__builtin_amdgcn_cosf(rr),
                               __builtin_amdgcn_sinf(rr)));
        }
        v.x = u[0]; v.y = u[1]; v.z = u[2]; v.w = u[3];
    }
    wtab[gid] = v;
}

__global__ __launch_bounds__(THREADS) void gsim_mfma(
        const float* __restrict__ x,
        const uint4* __restrict__ wtab,
        const float* __restrict__ radius,
        float* __restrict__ out) {
    const int bid = blockIdx.x;
    const int mt = bid & (MTILES - 1);   // m-tile (fast) -> same-kc blocks adjacent
    const int kc = bid >> 5;             // k-chunk
    const int t = threadIdx.x;
    const int wave = t >> 6, lane = t & 63;
    const int o = lane & 15, kg = lane >> 4;

    // A-side: lane reads row (mt*64 + wave*16 + o), 4 floats per window
    const int row = mt * 64 + wave * 16 + o;
    const int t0 = kc * WPC;
    const float4* xp = (const float4*)x + ((size_t)row * (K_DIM / 4) + t0 * 4 + kg);
    const uint4* bp = wtab + (size_t)t0 * 64 + lane;

    f32x4 acc = {0.f, 0.f, 0.f, 0.f};

    // prologue: iteration 0's two windows
    float4 xc0 = xp[0], xc1 = xp[4];
    uint4  bc0 = bp[0], bc1 = bp[64];

    #pragma unroll 1
    for (int i = 0; i < ITERS; ++i) {
        const int ni = (i + 1 < ITERS) ? (i + 1) : i;  // last iter: harmless reload
        // issue next iteration's 4 loads; in flight across trig + 2 MFMAs
        float4 xn0 = xp[ni * 8],       xn1 = xp[ni * 8 + 4];
        uint4  bn0 = bp[ni * 128],     bn1 = bp[ni * 128 + 64];

        half8_t a0 = afrag(xc0);
        acc = __builtin_amdgcn_mfma_f32_16x16x32_f16(
                  a0, __builtin_bit_cast(half8_t, bc0), acc, 0, 0, 0);
        half8_t a1 = afrag(xc1);
        acc = __builtin_amdgcn_mfma_f32_16x16x32_f16(
                  a1, __builtin_bit_cast(half8_t, bc1), acc, 0, 0, 0);

        xc0 = xn0; xc1 = xn1; bc0 = bn0; bc1 = bn1;
    }

    // C/D layout: col = lane&15, row_in_tile = (lane>>4)*4 + reg  [m89]
    // Direct epilogue: scale and atomically accumulate into out (64 kc
    // contenders per address; fp-order variation ~1e-4 << 1.99 threshold).
    if (o < O_DIM) {
        const float sc = radius[0] * INV_SQRT_K;
        const int rbase = mt * 64 + wave * 16 + kg * 4;
        #pragma unroll
        for (int reg = 0; reg < 4; ++reg)
            atomicAdd(out + (size_t)(rbase + reg) * O_DIM + o, acc[reg] * sc);
    }
}

extern "C" void kernel_launch(void* const* d_in, const int* in_sizes, int n_in,
                              void* d_out, int out_size, void* d_ws, size_t ws_size,
                              hipStream_t stream) {
    const float* x      = (const float*)d_in[0];
    const float* w      = (const float*)d_in[1];
    const float* radius = (const float*)d_in[2];
    float* out = (float*)d_out;

    // ws: wtab[2048][64] uint4 (2 MB)
    uint4* wtab = (uint4*)d_ws;

    hipLaunchKernelGGL(wtab_kernel, dim3(NWIN * 64 / THREADS), dim3(THREADS),
                       0, stream, w, wtab, out);
    hipLaunchKernelGGL(gsim_mfma, dim3(MTILES * KCH), dim3(THREADS),
                       0, stream, x, wtab, radius, out);
}

// Round 11
// 55.774 us; speedup vs baseline: 2.6135x; 1.0019x over previous
//
#include <hip/hip_runtime.h>

// out[b,o] = radius * (1/sqrt(K)) * sum_k cos(c*(w[o,k]-x[b,k])),  c = 2*pi/8
//          = radius * (1/sqrt(K)) * sum_k [cos(cx)cos(cw) + sin(cx)sin(cw)]
// B=2048, K=32768, O=10.
// Round 11: dense x staging via global_load_lds (width 16) into a 2x16KB LDS
// double buffer, T3 minimum 2-phase schedule (STAGE next / compute cur / one
// barrier per step). Global source pre-swizzled (col16 ^= row&7) so the linear
// LDS dest + swizzled read is bank-conflict-free (rule #21). Each stage
// instruction covers 4 rows x 256B dense vs round-7's 16 rows x 64B scatter.
// wtab + atomic epilogue + folded zero-init: round-10 verbatim.

typedef _Float16 half2_t __attribute__((ext_vector_type(2)));
typedef _Float16 half8_t __attribute__((ext_vector_type(8)));
typedef float f32x4 __attribute__((ext_vector_type(4)));

#define K_DIM 32768
#define B_DIM 2048
#define O_DIM 10
#define NWIN 2048               // one window = 16 x-ks (one MFMA)
#define KCH 64                  // K-chunks
#define WPC (NWIN / KCH)        // 32 windows per chunk
#define BK 64                   // floats per staging step
#define STEPS 8                 // 512 / 64
#define WINS 4                  // windows per step
#define MTILES (B_DIM / 64)     // 32
#define THREADS 256
#define INV_SQRT_K 0.005524271728019903f

// hardware v_sin/v_cos take REVOLUTIONS: sin(2*pi*r). c*x radians -> r = x/8.

__device__ __forceinline__ half2_t pack_cs(float c, float s) {
    return __builtin_bit_cast(half2_t, __builtin_amdgcn_cvt_pkrtz(c, s));
}

// A fragment from 4 consecutive x floats: (cos,sin) f16 pairs -> 8 f16
__device__ __forceinline__ half8_t afrag(float4 xc) {
    const float* xf = (const float*)&xc;
    uint4 au;
    unsigned u[4];
    #pragma unroll
    for (int j = 0; j < 4; ++j) {
        float rr = xf[j] * 0.125f;            // revolutions
        u[j] = __builtin_bit_cast(unsigned,
                   pack_cs(__builtin_amdgcn_cosf(rr),
                           __builtin_amdgcn_sinf(rr)));
    }
    au.x = u[0]; au.y = u[1]; au.z = u[2]; au.w = u[3];
    return __builtin_bit_cast(half8_t, au);
}

__device__ __forceinline__ void gl_lds16(const float* g, float* l) {
    __builtin_amdgcn_global_load_lds(
        (const __attribute__((address_space(1))) unsigned int*)g,
        (__attribute__((address_space(3))) unsigned int*)l,
        16, 0, 0);
}

// B-fragment table: for window t, lane l: 16 bytes = (cos,sin) f16 pairs of
// w[o = l&15][k = t*16 + (l>>4)*4 + 0..3]; o >= 10 -> zeros.
// Blocks 0..79 additionally zero d_out (harness poisons once, no re-poison).
__global__ void wtab_kernel(const float* __restrict__ w,
                            uint4* __restrict__ wtab,
                            float* __restrict__ out) {
    if (blockIdx.x < (B_DIM * O_DIM) / THREADS)
        out[blockIdx.x * THREADS + threadIdx.x] = 0.f;

    int gid = blockIdx.x * THREADS + threadIdx.x;    // 2048*64 = 131072 exact
    int t = gid >> 6, l = gid & 63;
    int o = l & 15, kg = l >> 4;
    int k = t * 16 + kg * 4;
    uint4 v; v.x = v.y = v.z = v.w = 0u;
    if (o < O_DIM) {
        const float4 wv = *(const float4*)(w + (size_t)o * K_DIM + k);
        const float* wp = (const float*)&wv;
        unsigned u[4];
        #pragma unroll
        for (int j = 0; j < 4; ++j) {
            float rr = wp[j] * 0.125f;
            u[j] = __builtin_bit_cast(unsigned,
                       pack_cs(__builtin_amdgcn_cosf(rr),
                               __builtin_amdgcn_sinf(rr)));
        }
        v.x = u[0]; v.y = u[1]; v.z = u[2]; v.w = u[3];
    }
    wtab[gid] = v;
}

__global__ __launch_bounds__(THREADS) void gsim_mfma(
        const float* __restrict__ x,
        const uint4* __restrict__ wtab,
        const float* __restrict__ radius,
        float* __restrict__ out) {
    __shared__ float xtile[2][64 * BK];   // 2 x 16 KB

    const int bid = blockIdx.x;
    const int mt = bid & (MTILES - 1);    // m-tile (fast)
    const int kc = bid >> 5;              // k-chunk
    const int t = threadIdx.x;
    const int wave = t >> 6, lane = t & 63;
    const int o = lane & 15, kg = lane >> 4;

    // ---- staging geometry ----
    // issue i covers rows wave*16 + i*4 + (lane>>4); physical 16B slot u=lane&15
    // holds global col-slot g = u ^ (row&7)  (row&7 = (i*4+srh)&7).
    const int srh = lane >> 4;            // 0..3
    const int su  = lane & 15;            // 0..15
    const float* gx = x + (size_t)(mt * 64 + wave * 16 + srh) * K_DIM + kc * 512;

    // ---- compute geometry ----
    // lane (o,kg) window win: LDS float idx = wave*1024 + o*64
    //                         + (((win*4+kg) ^ (o&7)) * 4)
    const int o7 = o & 7;

    const uint4* bp = wtab + (size_t)(kc * WPC) * 64 + lane;

    f32x4 acc = {0.f, 0.f, 0.f, 0.f};

    // prologue: stage step 0 into buffer 0
    #pragma unroll
    for (int i = 0; i < 4; ++i) {
        const int r7 = (i * 4 + srh) & 7;
        gl_lds16(gx + (size_t)(i * 4) * K_DIM + ((su ^ r7) << 2),
                 &xtile[0][wave * 1024 + i * 256]);
    }

    #pragma unroll
    for (int s = 0; s < STEPS; ++s) {
        __syncthreads();   // buf[s&1] loads drained & visible; prev reads done

        // stage step s+1 into the other buffer; in flight across compute
        if (s + 1 < STEPS) {
            #pragma unroll
            for (int i = 0; i < 4; ++i) {
                const int r7 = (i * 4 + srh) & 7;
                gl_lds16(gx + (size_t)(i * 4) * K_DIM + (s + 1) * BK
                            + ((su ^ r7) << 2),
                         &xtile[(s + 1) & 1][wave * 1024 + i * 256]);
            }
        }

        // wtab fragments for this step (L2-resident)
        uint4 bc[WINS];
        #pragma unroll
        for (int j = 0; j < WINS; ++j)
            bc[j] = bp[(size_t)(s * WINS + j) * 64];

        #pragma unroll
        for (int win = 0; win < WINS; ++win) {
            const float4 xv = *(const float4*)
                &xtile[s & 1][wave * 1024 + o * 64
                              + ((((win << 2) + kg) ^ o7) << 2)];
            acc = __builtin_amdgcn_mfma_f32_16x16x32_f16(
                      afrag(xv), __builtin_bit_cast(half8_t, bc[win]),
                      acc, 0, 0, 0);
        }
    }

    // C/D layout: col = lane&15, row_in_tile = (lane>>4)*4 + reg  [m89]
    // Atomic epilogue (64 kc contenders per address).
    if (o < O_DIM) {
        const float sc = radius[0] * INV_SQRT_K;
        const int rbase = mt * 64 + wave * 16 + kg * 4;
        #pragma unroll
        for (int reg = 0; reg < 4; ++reg)
            atomicAdd(out + (size_t)(rbase + reg) * O_DIM + o, acc[reg] * sc);
    }
}

extern "C" void kernel_launch(void* const* d_in, const int* in_sizes, int n_in,
                              void* d_out, int out_size, void* d_ws, size_t ws_size,
                              hipStream_t stream) {
    const float* x      = (const float*)d_in[0];
    const float* w      = (const float*)d_in[1];
    const float* radius = (const float*)d_in[2];
    float* out = (float*)d_out;

    // ws: wtab[2048][64] uint4 (2 MB)
    uint4* wtab = (uint4*)d_ws;

    hipLaunchKernelGGL(wtab_kernel, dim3(NWIN * 64 / THREADS), dim3(THREADS),
                       0, stream, w, wtab, out);
    hipLaunchKernelGGL(gsim_mfma, dim3(MTILES * KCH), dim3(THREADS),
                       0, stream, x, wtab, radius, out);
}